// Round 3
// baseline (762.731 us; speedup 1.0000x reference)
//
#include <hip/hip_runtime.h>

// LocalizeAttention: out[b,h,n,f,c] = x[b,h, n_shifted(n,f), c] or 0 at the
// zero-padded boundary. Fixed: b*h=16, H=W=D=24 (N=13824), d=32 (8 float4),
// FN=27. One WG per (bh,ii,jj) pencil; 576 threads = 9 waves.
//
// r3: (1) wave w DMA-stages pencil w via global_load_lds width=16 (no VGPR
// round trip; pencil rows are contiguous in global AND LDS = linear-dest
// constraint satisfied); (2) write loop = exactly 9 unrolled iterations with
// incremental p/lds-index update (no div/mod in loop); (3) bijective
// XCD-chunked block swizzle so each XCD's read set (~3.5 MB) fits its 4 MB L2.

typedef float v4f __attribute__((ext_vector_type(4)));
typedef const __attribute__((address_space(1))) v4f* gptr_t;
typedef __attribute__((address_space(3))) v4f* lptr_t;

constexpr int H = 24, W = 24, D = 24;
constexpr int N = H * W * D;            // 13824
constexpr int FN = 27;
constexpr int BH = 16;                  // b*h
constexpr int PLEN = D + 2;             // 26 rows per pencil incl halo
constexpr int P_N4 = PLEN * 8;          // 208 float4 per pencil
constexpr int LDS_N4 = 9 * P_N4;        // 1872 float4 = 29,952 B
constexpr int NT = 576;                 // 9 waves: wave <-> pencil 1:1
constexpr int NWG = BH * H * W;         // 9216 (% 8 == 0 -> clean XCD chunks)

__global__ __launch_bounds__(NT) void localize_kernel(
    const v4f* __restrict__ x4, v4f* __restrict__ out4) {
  __shared__ v4f lds[LDS_N4];
  const int tid  = threadIdx.x;
  const int lane = tid & 63;
  const int wv   = tid >> 6;            // wave index == pencil index 0..8

  // XCD-chunked bijective swizzle: XCD x gets wgs [x*1152, (x+1)*1152)
  const int bid = blockIdx.x;
  const int wg  = (bid & 7) * (NWG / 8) + (bid >> 3);

  const int bh  = wg / (H * W);
  const int rem = wg - bh * (H * W);
  const int ii  = rem / W;
  const int jj  = rem - ii * W;

  // ---- stage: wave wv owns pencil wv = (di+1)*3 + (dj+1) ----
  const int pdi = wv / 3;               // 0..2
  const int si  = ii + pdi - 1;
  const int sj  = jj + (wv - pdi * 3) - 1;
  const int pbase = wv * P_N4;          // float4 offset of this pencil in LDS

  if ((unsigned)si < (unsigned)H && (unsigned)sj < (unsigned)W) {
    // zero the 2 halo rows (srck=0 and 25): 16 float4
    if (lane < 16) {
      int off = (lane < 8) ? lane : (25 * 8 + (lane - 8));
      lds[pbase + off] = (v4f)(0.0f);
    }
    // DMA rows sk=0..23 -> srck=1..24: 192 contiguous float4, 3 x 64 lanes
    const v4f* g = x4 + (((bh * H + si) * W + sj) * D) * 8;
#pragma unroll
    for (int it = 0; it < 3; ++it) {
      const v4f* gp = g + it * 64 + lane;          // per-lane global src
      v4f* lp = &lds[pbase + 8 + it * 64];         // wave-uniform LDS base
      __builtin_amdgcn_global_load_lds((gptr_t)gp, (lptr_t)lp, 16, 0, 0);
    }
  } else {
    // OOB pencil: all zeros (208 float4 = 3.25 x 64 lanes)
#pragma unroll
    for (int it = 0; it < 4; ++it) {
      int off = it * 64 + lane;
      if (off < P_N4) lds[pbase + off] = (v4f)(0.0f);
    }
  }
  __syncthreads();   // drains vmcnt (global_load_lds) + lgkm

  // ---- write: 5184 float4 / 576 threads = exactly 9 iterations ----
  // o = tid + i*576; c4 = tid&7 (576%8==0); t = (tid>>3) + i*72.
  // t = kk*27 + f, f = p*3 + fm3. dt=72 => kk+=2, p+=6 (fm3 invariant),
  // carry: p>=9 -> p-=9, kk+=1.  LDS row = p*26 + kk + fm3.
  const int c4 = tid & 7;
  int t  = tid >> 3;                    // 0..71
  int kk = t / FN;
  int f  = t - kk * FN;
  int p  = f / 3;
  const int fm3 = f - p * 3;
  int ldsidx = (p * PLEN + kk + fm3) * 8 + c4;
  const int base = (bh * N + ii * (W * D) + jj * D) * (FN * 8) + tid;
#pragma unroll
  for (int i = 0; i < 9; ++i) {
    v4f v = lds[ldsidx];
    __builtin_nontemporal_store(v, &out4[base + i * NT]);
    // incremental index update (no div/mod): drow = 6*26+2 = 158, or
    // on carry (p>=9): (6-9)*26 + (2+1) = -75
    p += 6;
    int drow = 158;
    if (p >= 9) { p -= 9; drow = -75; }
    ldsidx += drow * 8;
  }
}

extern "C" void kernel_launch(void* const* d_in, const int* in_sizes, int n_in,
                              void* d_out, int out_size, void* d_ws, size_t ws_size,
                              hipStream_t stream) {
  (void)in_sizes; (void)n_in; (void)out_size; (void)d_ws; (void)ws_size;
  const v4f* x4 = (const v4f*)d_in[0];
  v4f* out4 = (v4f*)d_out;
  localize_kernel<<<NWG, NT, 0, stream>>>(x4, out4);
}

// Round 6
// 759.250 us; speedup vs baseline: 1.0046x; 1.0046x over previous
//
#include <hip/hip_runtime.h>

// LocalizeAttention: out[b,h,n,f,c] = x[b,h, n_shifted(n,f), c] or 0 at the
// zero-padded boundary. Fixed: b*h=16, H=W=D=24 (N=13824), d=32 (8 float4),
// FN=27. One WG per (bh,ii,jj) pencil; 576 threads = 9 waves.
//
// r6 == r4/r5 resubmit (both were infra failures, no data). A/B vs r3:
// identical except NT stores -> PLAIN stores. Theory: the nt cache bit
// defeats L2 write-combining and caps the 764 MB write stream at ~2.9 TB/s
// (vs 6.3 TB/s the harness fill achieves with plain stores).

typedef float v4f __attribute__((ext_vector_type(4)));
typedef const __attribute__((address_space(1))) v4f* gptr_t;
typedef __attribute__((address_space(3))) v4f* lptr_t;

constexpr int H = 24, W = 24, D = 24;
constexpr int N = H * W * D;            // 13824
constexpr int FN = 27;
constexpr int BH = 16;                  // b*h
constexpr int PLEN = D + 2;             // 26 rows per pencil incl halo
constexpr int P_N4 = PLEN * 8;          // 208 float4 per pencil
constexpr int LDS_N4 = 9 * P_N4;        // 1872 float4 = 29,952 B
constexpr int NT = 576;                 // 9 waves: wave <-> pencil 1:1
constexpr int NWG = BH * H * W;         // 9216 (% 8 == 0 -> clean XCD chunks)

__global__ __launch_bounds__(NT) void localize_kernel(
    const v4f* __restrict__ x4, v4f* __restrict__ out4) {
  __shared__ v4f lds[LDS_N4];
  const int tid  = threadIdx.x;
  const int lane = tid & 63;
  const int wv   = tid >> 6;            // wave index == pencil index 0..8

  // XCD-chunked bijective swizzle: XCD x gets wgs [x*1152, (x+1)*1152)
  const int bid = blockIdx.x;
  const int wg  = (bid & 7) * (NWG / 8) + (bid >> 3);

  const int bh  = wg / (H * W);
  const int rem = wg - bh * (H * W);
  const int ii  = rem / W;
  const int jj  = rem - ii * W;

  // ---- stage: wave wv owns pencil wv = (di+1)*3 + (dj+1) ----
  const int pdi = wv / 3;               // 0..2
  const int si  = ii + pdi - 1;
  const int sj  = jj + (wv - pdi * 3) - 1;
  const int pbase = wv * P_N4;          // float4 offset of this pencil in LDS

  if ((unsigned)si < (unsigned)H && (unsigned)sj < (unsigned)W) {
    // zero the 2 halo rows (srck=0 and 25): 16 float4
    if (lane < 16) {
      int off = (lane < 8) ? lane : (25 * 8 + (lane - 8));
      lds[pbase + off] = (v4f)(0.0f);
    }
    // DMA rows sk=0..23 -> srck=1..24: 192 contiguous float4, 3 x 64 lanes
    const v4f* g = x4 + (((bh * H + si) * W + sj) * D) * 8;
#pragma unroll
    for (int it = 0; it < 3; ++it) {
      const v4f* gp = g + it * 64 + lane;          // per-lane global src
      v4f* lp = &lds[pbase + 8 + it * 64];         // wave-uniform LDS base
      __builtin_amdgcn_global_load_lds((gptr_t)gp, (lptr_t)lp, 16, 0, 0);
    }
  } else {
    // OOB pencil: all zeros (208 float4 = 3.25 x 64 lanes)
#pragma unroll
    for (int it = 0; it < 4; ++it) {
      int off = it * 64 + lane;
      if (off < P_N4) lds[pbase + off] = (v4f)(0.0f);
    }
  }
  __syncthreads();   // drains vmcnt (global_load_lds) + lgkm

  // ---- write: 5184 float4 / 576 threads = exactly 9 iterations ----
  // o = tid + i*576; c4 = tid&7 (576%8==0); t = (tid>>3) + i*72.
  // t = kk*27 + f, f = p*3 + fm3. dt=72 => kk+=2, p+=6 (fm3 invariant),
  // carry: p>=9 -> p-=9, kk+=1.  LDS row = p*26 + kk + fm3.
  const int c4 = tid & 7;
  int t  = tid >> 3;                    // 0..71
  int kk = t / FN;
  int f  = t - kk * FN;
  int p  = f / 3;
  const int fm3 = f - p * 3;
  int ldsidx = (p * PLEN + kk + fm3) * 8 + c4;
  const int base = (bh * N + ii * (W * D) + jj * D) * (FN * 8) + tid;
#pragma unroll
  for (int i = 0; i < 9; ++i) {
    v4f v = lds[ldsidx];
    out4[base + i * NT] = v;            // PLAIN store (the A/B change)
    // incremental index update (no div/mod): drow = 6*26+2 = 158, or
    // on carry (p>=9): (6-9)*26 + (2+1) = -75
    p += 6;
    int drow = 158;
    if (p >= 9) { p -= 9; drow = -75; }
    ldsidx += drow * 8;
  }
}

extern "C" void kernel_launch(void* const* d_in, const int* in_sizes, int n_in,
                              void* d_out, int out_size, void* d_ws, size_t ws_size,
                              hipStream_t stream) {
  (void)in_sizes; (void)n_in; (void)out_size; (void)d_ws; (void)ws_size;
  const v4f* x4 = (const v4f*)d_in[0];
  v4f* out4 = (v4f*)d_out;
  localize_kernel<<<NWG, NT, 0, stream>>>(x4, out4);
}